// Round 6
// baseline (396.157 us; speedup 1.0000x reference)
//
#include <hip/hip_runtime.h>

typedef unsigned int uint;
typedef unsigned short ushort;
typedef __bf16 bf16x8 __attribute__((ext_vector_type(8)));
typedef float f32x4 __attribute__((ext_vector_type(4)));
typedef uint u32x4 __attribute__((ext_vector_type(4)));

#define DEV static __device__ __forceinline__

#define BATCH 2
#define SEQ 2048
#define DMODEL 2048
#define NHEADS 16
#define DHEAD 128
#define MROWS (BATCH*SEQ)           // 4096
#define RSCALE 0.08838834764831845f // 1/sqrt(128)
#define LOG2E  1.4426950408889634f

DEV float fast_exp2(float x) { return __builtin_amdgcn_exp2f(x); }

DEV bf16x8 as_frag(u32x4 v) { return __builtin_bit_cast(bf16x8, v); }
DEV ushort f2bf(float f) {
  uint u = __builtin_bit_cast(uint, f);
  u += 0x7fffu + ((u >> 16) & 1u);   // RNE
  return (ushort)(u >> 16);
}
DEV u32x4 lds_ld16(const ushort* p) { return *(const u32x4*)p; }

// async global->LDS, 16B per lane; LDS dest = wave-uniform base + lane*16
DEV void async_cp16(const ushort* g, ushort* l) {
  __builtin_amdgcn_global_load_lds(
      (const __attribute__((address_space(1))) uint*)g,
      (__attribute__((address_space(3))) uint*)l, 16, 0, 0);
}

// ---------------------------------------------------------------------------
// Fused preprocessing: x f32->bf16 convert + 4 weight transposes (f32->bf16)
// 64x64 transpose tiles: 256B read segments, 128B write segments.
// block ranges: [0,8192) convert; [8192,11264) Wq/Wk/Wv T; [11264,12288) Wo T
// ---------------------------------------------------------------------------
__global__ __launch_bounds__(256) void prep(
    const float* __restrict__ x,
    const float* __restrict__ Wq, const float* __restrict__ Wk,
    const float* __restrict__ Wv, const float* __restrict__ Wo,
    ushort* __restrict__ xb, ushort* __restrict__ WqT,
    ushort* __restrict__ WkT, ushort* __restrict__ WvT,
    ushort* __restrict__ WoT)
{
  int id = blockIdx.x;
  if (id < 8192) {
    int i = id * 256 + threadIdx.x;       // n4 = 2,097,152 exactly
    float4 v = ((const float4*)x)[i];
    union { ushort u[4]; uint2 w; } o;
    o.u[0] = f2bf(v.x); o.u[1] = f2bf(v.y); o.u[2] = f2bf(v.z); o.u[3] = f2bf(v.w);
    ((uint2*)xb)[i] = o.w;
    return;
  }
  __shared__ ushort t[64][65];
  id -= 8192;
  const float* src; ushort* dst; int R, C, c0, r0;
  if (id < 3072) {
    int which = id >> 10;                 // /1024
    int r = id & 1023;
    int slice = r >> 6;                   // 64 tiles per slice (2 x 32)
    int rem = r & 63;
    int tx = rem & 1, ty = rem >> 1;
    const float* S[3] = {Wq, Wk, Wv};
    ushort* D[3] = {WqT, WkT, WvT};
    src = S[which] + (size_t)slice * DMODEL * DHEAD;
    dst = D[which] + (size_t)slice * DMODEL * DHEAD;
    R = DMODEL; C = DHEAD; c0 = tx * 64; r0 = ty * 64;
  } else {
    id -= 3072;
    int tx = id & 31, ty = id >> 5;
    src = Wo; dst = WoT; R = DMODEL; C = DMODEL; c0 = tx * 64; r0 = ty * 64;
  }
  int xx = threadIdx.x & 63, yy = threadIdx.x >> 6;
  #pragma unroll
  for (int i = 0; i < 64; i += 4)
    t[yy + i][xx] = f2bf(src[(size_t)(r0 + yy + i) * C + (c0 + xx)]);
  __syncthreads();
  #pragma unroll
  for (int i = 0; i < 64; i += 4)
    dst[(size_t)(c0 + yy + i) * R + (r0 + xx)] = t[xx][yy + i];
}

// ---------------------------------------------------------------------------
// One of Q/K/V projection GEMM (m97-style), launched 3x for visibility.
// A = xb [4096][2048] bf16, Bt per head [128 e][2048 d] bf16.
// which: 0=Q (scaled by RSCALE*LOG2E), 1=K, 2=V (transposed write [bh][e][pos])
// ---------------------------------------------------------------------------
__global__ __launch_bounds__(256, 4) void gemm_qkv(
    const ushort* __restrict__ xb, const ushort* __restrict__ BtAll,
    const float* __restrict__ biasAll, ushort* __restrict__ Out, int which)
{
  int mt = blockIdx.x;       // 0..31
  int h  = blockIdx.y;       // 0..15
  const ushort* Bt = BtAll + (size_t)h * DHEAD * DMODEL;
  const float* bias = biasAll + h * DHEAD;

  __shared__ __align__(16) ushort As[128 * 64];
  __shared__ __align__(16) ushort Bs[128 * 64];

  int tid = threadIdx.x, lane = tid & 63, w = tid >> 6;
  int wm = w >> 1, wn = w & 1;
  int l16 = lane & 15, quad = lane >> 4;

  const ushort* Ag = xb + (size_t)(mt * 128) * DMODEL;

  int soff[4]; int sc[4];
  #pragma unroll
  for (int t = 0; t < 4; t++) {
    int c = w * 4 + t;
    int r = c * 8 + (lane >> 3);
    int p = lane & 7;
    int g = p ^ (r & 7);
    soff[t] = r * DMODEL + g * 8;
    sc[t] = c * 512;
  }

  f32x4 acc[4][4] = {};

  for (int k0 = 0; k0 < DMODEL; k0 += 64) {
    __syncthreads();
    #pragma unroll
    for (int t = 0; t < 4; t++) {
      async_cp16(Ag + soff[t] + k0, As + sc[t]);
      async_cp16(Bt + soff[t] + k0, Bs + sc[t]);
    }
    __syncthreads();
    #pragma unroll
    for (int kk = 0; kk < 2; kk++) {
      bf16x8 a[4], b[4];
      #pragma unroll
      for (int i = 0; i < 4; i++) {
        int row = wm * 64 + i * 16 + l16;
        int p = (kk * 4 + quad) ^ (l16 & 7);
        a[i] = as_frag(lds_ld16(As + row * 64 + p * 8));
      }
      #pragma unroll
      for (int i = 0; i < 4; i++) {
        int row = wn * 64 + i * 16 + l16;
        int p = (kk * 4 + quad) ^ (l16 & 7);
        b[i] = as_frag(lds_ld16(Bs + row * 64 + p * 8));
      }
      #pragma unroll
      for (int i = 0; i < 4; i++)
        #pragma unroll
        for (int j = 0; j < 4; j++)
          acc[i][j] = __builtin_amdgcn_mfma_f32_16x16x32_bf16(a[i], b[j], acc[i][j], 0, 0, 0);
    }
  }

  float scale = (which == 0) ? RSCALE * LOG2E : 1.0f;
  #pragma unroll
  for (int i = 0; i < 4; i++) {
    #pragma unroll
    for (int j = 0; j < 4; j++) {
      int col = wn * 64 + j * 16 + l16;       // e
      float bb = bias[col];
      #pragma unroll
      for (int r = 0; r < 4; r++) {
        int row = mt * 128 + wm * 64 + i * 16 + quad * 4 + r;
        int b_ = row >> 11, p = row & 2047;
        int bh = b_ * NHEADS + h;
        ushort val = f2bf((acc[i][j][r] + bb) * scale);
        if (which == 2) {
          Out[((size_t)bh * DHEAD + col) * SEQ + p] = val;  // Vt [bh][e][pos]
        } else {
          Out[((size_t)bh * SEQ + p) * DHEAD + col] = val;  // [bh][pos][e]
        }
      }
    }
  }
}

// ---------------------------------------------------------------------------
// Flash attention (causal), 1 barrier/chunk: K/V double-buffered async
// staging overlaps compute; Ps is wave-private (no barrier). exp2 domain.
// Block a does qtiles {31-a, a}; 512 blocks, 2 blocks/CU.
// ---------------------------------------------------------------------------
__global__ __launch_bounds__(256, 2) void flash_attn(
    const ushort* __restrict__ Q, const ushort* __restrict__ K,
    const ushort* __restrict__ Vt, ushort* __restrict__ Z)
{
  int a  = blockIdx.x;   // 0..15
  int bh = blockIdx.y;   // 0..31
  const ushort* Qg = Q + (size_t)bh * SEQ * DHEAD;   // [2048][128]
  const ushort* Kg = K + (size_t)bh * SEQ * DHEAD;
  const ushort* Vg = Vt + (size_t)bh * DHEAD * SEQ;  // [128][2048]

  __shared__ __align__(16) ushort Ks[2][64 * 128];   // 32 KB
  __shared__ __align__(16) ushort Vs[2][128 * 64];   // 32 KB
  __shared__ __align__(16) ushort Ps[64 * 72];       // 9 KB (wave-private rows)

  int tid = threadIdx.x, lane = tid & 63, w = tid >> 6;
  int l16 = lane & 15, quad = lane >> 4;

  int kOff[4], vOff[4], cLds[4];
  #pragma unroll
  for (int t = 0; t < 4; t++) {
    int c = w * 4 + t;
    cLds[t] = c * 512;
    int rk = c * 4 + (lane >> 4);
    int pk = lane & 15;
    int gk = (pk & 8) | ((pk & 7) ^ (rk & 7));
    kOff[t] = rk * DHEAD + gk * 8;
    int ev = c * 8 + (lane >> 3);
    int pv = lane & 7;
    int gv = pv ^ (ev & 7);
    vOff[t] = ev * SEQ + gv * 8;
  }

  #pragma unroll
  for (int ph = 0; ph < 2; ph++) {
    int qt = ph ? a : (31 - a);
    int q0 = qt * 64;

    bf16x8 qf[4];
    int qrow = q0 + w * 16 + l16;
    #pragma unroll
    for (int kb = 0; kb < 4; kb++)
      qf[kb] = as_frag(*(const u32x4*)(Qg + qrow * DHEAD + kb * 32 + quad * 8));

    float m_i[4], l_i[4];
    #pragma unroll
    for (int i = 0; i < 4; i++) { m_i[i] = -1e30f; l_i[i] = 0.0f; }
    f32x4 zacc[8] = {};

    // prologue: stage chunk 0 into buffer 0
    #pragma unroll
    for (int t = 0; t < 4; t++) {
      async_cp16(Kg + kOff[t], Ks[0] + cLds[t]);
      async_cp16(Vg + vOff[t], Vs[0] + cLds[t]);
    }
    __syncthreads();   // staging 0 visible (vmcnt drained)

    for (int j = 0; j <= qt; j++) {
      int cur = j & 1;
      // issue async staging for chunk j+1 — overlaps this chunk's compute
      if (j < qt) {
        int k1 = (j + 1) * 64;
        #pragma unroll
        for (int t = 0; t < 4; t++) {
          async_cp16(Kg + k1 * DHEAD + kOff[t], Ks[cur ^ 1] + cLds[t]);
          async_cp16(Vg + k1 + vOff[t], Vs[cur ^ 1] + cLds[t]);
        }
      }
      const ushort* KsC = Ks[cur];
      const ushort* VsC = Vs[cur];

      // S = Q K^T
      f32x4 s[4] = {};
      #pragma unroll
      for (int kb = 0; kb < 4; kb++) {
        #pragma unroll
        for (int n = 0; n < 4; n++) {
          int r = n * 16 + l16;
          int ug = kb * 4 + quad;
          int p = (ug & 8) | ((ug & 7) ^ (r & 7));
          bf16x8 b = as_frag(lds_ld16(KsC + r * 128 + p * 8));
          s[n] = __builtin_amdgcn_mfma_f32_16x16x32_bf16(qf[kb], b, s[n], 0, 0, 0);
        }
      }
      // causal mask on diagonal chunk only (s already in exp2 domain)
      if (j == qt) {
        #pragma unroll
        for (int n = 0; n < 4; n++)
          #pragma unroll
          for (int i = 0; i < 4; i++) {
            int qr = 16 * w + quad * 4 + i;
            int kr = n * 16 + l16;
            if (kr > qr) s[n][i] = -1e30f;
          }
      }
      float mx[4];
      #pragma unroll
      for (int i = 0; i < 4; i++)
        mx[i] = fmaxf(fmaxf(s[0][i], s[1][i]), fmaxf(s[2][i], s[3][i]));
      #pragma unroll
      for (int off = 1; off < 16; off <<= 1)
        #pragma unroll
        for (int i = 0; i < 4; i++)
          mx[i] = fmaxf(mx[i], __shfl_xor(mx[i], off, 64));

      float alpha[4], rsum[4];
      #pragma unroll
      for (int i = 0; i < 4; i++) {
        float mn = fmaxf(m_i[i], mx[i]);
        alpha[i] = fast_exp2(m_i[i] - mn);
        m_i[i] = mn;
        rsum[i] = 0.0f;
      }
      #pragma unroll
      for (int n = 0; n < 4; n++)
        #pragma unroll
        for (int i = 0; i < 4; i++) {
          float p = fast_exp2(s[n][i] - m_i[i]);
          rsum[i] += p;
          int row = 16 * w + quad * 4 + i, col = n * 16 + l16;
          Ps[row * 72 + col] = f2bf(p);
        }
      #pragma unroll
      for (int off = 1; off < 16; off <<= 1)
        #pragma unroll
        for (int i = 0; i < 4; i++)
          rsum[i] += __shfl_xor(rsum[i], off, 64);
      #pragma unroll
      for (int i = 0; i < 4; i++) l_i[i] = l_i[i] * alpha[i] + rsum[i];
      #pragma unroll
      for (int n = 0; n < 8; n++)
        #pragma unroll
        for (int i = 0; i < 4; i++) zacc[n][i] *= alpha[i];

      // O += P V  (Ps rows are wave-private: compiler's lgkmcnt handles WAR)
      #pragma unroll
      for (int kk = 0; kk < 2; kk++) {
        bf16x8 af = as_frag(lds_ld16(Ps + (w * 16 + l16) * 72 + (kk * 4 + quad) * 8));
        #pragma unroll
        for (int n = 0; n < 8; n++) {
          int e = n * 16 + l16;
          int ug = kk * 4 + quad;
          int p = ug ^ (e & 7);
          bf16x8 b = as_frag(lds_ld16(VsC + e * 64 + p * 8));
          zacc[n] = __builtin_amdgcn_mfma_f32_16x16x32_bf16(af, b, zacc[n], 0, 0, 0);
        }
      }
      __syncthreads();   // reads of buf[cur] done; staging j+1 drained
    }

    // epilogue: Z[b*2048+pos][h*128+e] = zacc / l  (bf16)
    int b_ = bh >> 4, h = bh & 15;
    #pragma unroll
    for (int n = 0; n < 8; n++)
      #pragma unroll
      for (int i = 0; i < 4; i++) {
        int row = q0 + 16 * w + quad * 4 + i;
        int col = h * DHEAD + n * 16 + l16;
        Z[((size_t)(b_ * SEQ + row)) * DMODEL + col] = f2bf(zacc[n][i] / l_i[i]);
      }
  }
}

// ---------------------------------------------------------------------------
// Output projection (m97-style): out f32 = Z bf16 * WoT + bO
// ---------------------------------------------------------------------------
__global__ __launch_bounds__(256, 4) void gemm_out(
    const ushort* __restrict__ Zin, const ushort* __restrict__ WoT,
    const float* __restrict__ bO, float* __restrict__ out)
{
  int mt = blockIdx.x, ntile = blockIdx.y;
  __shared__ __align__(16) ushort As[128 * 64];
  __shared__ __align__(16) ushort Bs[128 * 64];
  int tid = threadIdx.x, lane = tid & 63, w = tid >> 6;
  int wm = w >> 1, wn = w & 1;
  int l16 = lane & 15, quad = lane >> 4;

  const ushort* Ag = Zin + (size_t)(mt * 128) * DMODEL;
  const ushort* Bg = WoT + (size_t)(ntile * 128) * DMODEL;

  int soff[4]; int sc[4];
  #pragma unroll
  for (int t = 0; t < 4; t++) {
    int c = w * 4 + t;
    int r = c * 8 + (lane >> 3);
    int p = lane & 7;
    int g = p ^ (r & 7);
    soff[t] = r * DMODEL + g * 8;
    sc[t] = c * 512;
  }

  f32x4 acc[4][4] = {};
  for (int k0 = 0; k0 < DMODEL; k0 += 64) {
    __syncthreads();
    #pragma unroll
    for (int t = 0; t < 4; t++) {
      async_cp16(Ag + soff[t] + k0, As + sc[t]);
      async_cp16(Bg + soff[t] + k0, Bs + sc[t]);
    }
    __syncthreads();
    #pragma unroll
    for (int kk = 0; kk < 2; kk++) {
      bf16x8 a[4], b[4];
      #pragma unroll
      for (int i = 0; i < 4; i++) {
        int row = wm * 64 + i * 16 + l16;
        int p = (kk * 4 + quad) ^ (l16 & 7);
        a[i] = as_frag(lds_ld16(As + row * 64 + p * 8));
      }
      #pragma unroll
      for (int i = 0; i < 4; i++) {
        int row = wn * 64 + i * 16 + l16;
        int p = (kk * 4 + quad) ^ (l16 & 7);
        b[i] = as_frag(lds_ld16(Bs + row * 64 + p * 8));
      }
      #pragma unroll
      for (int i = 0; i < 4; i++)
        #pragma unroll
        for (int j = 0; j < 4; j++)
          acc[i][j] = __builtin_amdgcn_mfma_f32_16x16x32_bf16(a[i], b[j], acc[i][j], 0, 0, 0);
    }
  }
  #pragma unroll
  for (int i = 0; i < 4; i++) {
    #pragma unroll
    for (int j = 0; j < 4; j++) {
      int col = ntile * 128 + wn * 64 + j * 16 + l16;
      float bb = bO[col];
      #pragma unroll
      for (int r = 0; r < 4; r++) {
        int row = mt * 128 + wm * 64 + i * 16 + quad * 4 + r;
        out[(size_t)row * DMODEL + col] = acc[i][j][r] + bb;
      }
    }
  }
}

// ---------------------------------------------------------------------------
extern "C" void kernel_launch(void* const* d_in, const int* in_sizes, int n_in,
                              void* d_out, int out_size, void* d_ws, size_t ws_size,
                              hipStream_t stream)
{
  const float* x  = (const float*)d_in[0];
  const float* Wq = (const float*)d_in[1];
  const float* Wk = (const float*)d_in[2];
  const float* Wv = (const float*)d_in[3];
  const float* Wo = (const float*)d_in[4];
  const float* bQ = (const float*)d_in[5];
  const float* bK = (const float*)d_in[6];
  const float* bV = (const float*)d_in[7];
  const float* bO = (const float*)d_in[8];
  float* out = (float*)d_out;

  ushort* ws = (ushort*)d_ws;
  const size_t WSZ = (size_t)NHEADS * DHEAD * DMODEL;       // 4,194,304
  const size_t QSZ = (size_t)BATCH * NHEADS * SEQ * DHEAD;  // 8,388,608
  ushort* xb  = ws;
  ushort* WqT = xb + (size_t)MROWS * DMODEL;
  ushort* WkT = WqT + WSZ;
  ushort* WvT = WkT + WSZ;
  ushort* WoT = WvT + WSZ;
  ushort* Qb  = WoT + (size_t)DMODEL * DMODEL;
  ushort* Kb  = Qb + QSZ;
  ushort* VtB = Kb + QSZ;
  ushort* Zb  = VtB + QSZ;

  dim3 tb(256);
  prep<<<dim3(12288), tb, 0, stream>>>(x, Wq, Wk, Wv, Wo,
                                       xb, WqT, WkT, WvT, WoT);

  gemm_qkv<<<dim3(32, 16), tb, 0, stream>>>(xb, WqT, bQ, Qb, 0);
  gemm_qkv<<<dim3(32, 16), tb, 0, stream>>>(xb, WkT, bK, Kb, 1);
  gemm_qkv<<<dim3(32, 16), tb, 0, stream>>>(xb, WvT, bV, VtB, 2);

  flash_attn<<<dim3(16, 32), tb, 0, stream>>>(Qb, Kb, VtB, Zb);

  gemm_out<<<dim3(32, 16), tb, 0, stream>>>(Zb, WoT, bO, out);
}